// Round 2
// baseline (461.943 us; speedup 1.0000x reference)
//
#include <hip/hip_runtime.h>

typedef float v4f __attribute__((ext_vector_type(4)));
typedef short v8s __attribute__((ext_vector_type(8)));

#define ALPHA 0.2f
#define LOG2E 1.44269504088896340736f
#define NROW 8192
#define FIN 256
#define FOUT 64
#define JSPLIT 8
#define JCHUNK (NROW / JSPLIT) /* 1024 */
#define NSTEP (JCHUNK / 32)    /* 32 */

static __device__ __forceinline__ unsigned short f2bf(float f) {
  unsigned int u = __builtin_bit_cast(unsigned int, f);
  u += 0x7fff + ((u >> 16) & 1);
  return (unsigned short)(u >> 16);
}
static __device__ __forceinline__ float bf2f(unsigned short s) {
  unsigned int u = ((unsigned int)s) << 16;
  return __builtin_bit_cast(float, u);
}

// ---------------- Kernel 1: Wh = h@W (stored transposed, bf16), src, dst ---
__global__ __launch_bounds__(256) void k1_proj(
    const float* __restrict__ h, const float* __restrict__ edge,
    const float* __restrict__ W, const float* __restrict__ a,
    const float* __restrict__ We, unsigned short* __restrict__ whT,
    float* __restrict__ srcv, float* __restrict__ dstv) {
  __shared__ float Ws[FIN * FOUT];
  int tid = threadIdx.x;
  const float4* Wg = (const float4*)W;
  float4* Wl = (float4*)Ws;
#pragma unroll
  for (int it = 0; it < 16; ++it) Wl[it * 256 + tid] = Wg[it * 256 + tid];
  int lane = tid & 63;
  int wave = tid >> 6;
  float a1c = a[lane], a2c = a[64 + lane], a3c = a[128 + lane];
  float Wer[8];
#pragma unroll
  for (int k = 0; k < 8; ++k) Wer[k] = We[k * 64 + lane];
  __syncthreads();
  int rbase = blockIdx.x * 16 + wave * 4;
  for (int rr = 0; rr < 4; ++rr) {
    int r = rbase + rr;
    const float* hr = h + r * FIN;
    float acc = 0.f;
#pragma unroll 4
    for (int k = 0; k < FIN; k += 4) {
      float4 hv = *(const float4*)(hr + k);
      acc += hv.x * Ws[(k + 0) * 64 + lane];
      acc += hv.y * Ws[(k + 1) * 64 + lane];
      acc += hv.z * Ws[(k + 2) * 64 + lane];
      acc += hv.w * Ws[(k + 3) * 64 + lane];
    }
    float4 e0 = *(const float4*)(edge + r * 8);
    float4 e1 = *(const float4*)(edge + r * 8 + 4);
    float acc2 = e0.x * Wer[0] + e0.y * Wer[1] + e0.z * Wer[2] + e0.w * Wer[3] +
                 e1.x * Wer[4] + e1.y * Wer[5] + e1.z * Wer[6] + e1.w * Wer[7];
    float ps = acc * a1c + acc2 * a3c;
    float pd = acc * a2c;
#pragma unroll
    for (int off = 32; off >= 1; off >>= 1) {
      ps += __shfl_xor(ps, off);
      pd += __shfl_xor(pd, off);
    }
    whT[lane * NROW + r] = f2bf(acc);
    if (lane == 0) {
      srcv[r] = ps;
      dstv[r] = pd;
    }
  }
}

// ---------------- Kernel 1b: global max of dst ----------------------------
__global__ __launch_bounds__(256) void k1b_dstmax(const float* __restrict__ dstv,
                                                  float* __restrict__ dmax) {
  int tid = threadIdx.x;
  float m = -1e30f;
  for (int k = tid; k < NROW; k += 256) m = fmaxf(m, dstv[k]);
#pragma unroll
  for (int off = 32; off >= 1; off >>= 1) m = fmaxf(m, __shfl_xor(m, off));
  __shared__ float red[4];
  if ((tid & 63) == 0) red[tid >> 6] = m;
  __syncthreads();
  if (tid == 0) dmax[0] = fmaxf(fmaxf(red[0], red[1]), fmaxf(red[2], red[3]));
}

// ---------------- Kernel 2: fused masked-softmax-weight x Wh (MFMA) -------
struct Buf {
  int4 aj0, aj1;
  float4 d0, d1;
  v8s b0, b1, b2, b3;
};

static __device__ __forceinline__ void loadstep(
    Buf& B, const int* __restrict__ adj, const float* __restrict__ dstv,
    const unsigned short* __restrict__ whT, int row, int g, int m, int jj) {
  const int* ap = adj + (long)row * NROW + jj + g * 8;
  B.aj0 = *(const int4*)ap;
  B.aj1 = *(const int4*)(ap + 4);
  const float* dp = dstv + jj + g * 8;
  B.d0 = *(const float4*)dp;
  B.d1 = *(const float4*)(dp + 4);
  const unsigned short* wp = whT + jj + g * 8;
  B.b0 = *(const v8s*)(wp + (m + 0) * NROW);
  B.b1 = *(const v8s*)(wp + (m + 16) * NROW);
  B.b2 = *(const v8s*)(wp + (m + 32) * NROW);
  B.b3 = *(const v8s*)(wp + (m + 48) * NROW);
}

static __device__ __forceinline__ void computestep(const Buf& B, float sv,
                                                   float M2, v4f& a0, v4f& a1,
                                                   v4f& a2, v4f& a3,
                                                   float& ssum) {
  v8s aw;
#define WCALC(adji, dsti, slot)                                 \
  {                                                             \
    float x = sv + (dsti);                                      \
    float lr = fmaxf(x, ALPHA * x);                             \
    float w = exp2f(__builtin_fmaf(lr, LOG2E, -M2));            \
    unsigned short wb = ((adji) > 0) ? f2bf(w) : (unsigned short)0; \
    ssum += bf2f(wb);                                           \
    aw[slot] = (short)wb;                                       \
  }
  WCALC(B.aj0.x, B.d0.x, 0)
  WCALC(B.aj0.y, B.d0.y, 1)
  WCALC(B.aj0.z, B.d0.z, 2)
  WCALC(B.aj0.w, B.d0.w, 3)
  WCALC(B.aj1.x, B.d1.x, 4)
  WCALC(B.aj1.y, B.d1.y, 5)
  WCALC(B.aj1.z, B.d1.z, 6)
  WCALC(B.aj1.w, B.d1.w, 7)
#undef WCALC
  a0 = __builtin_amdgcn_mfma_f32_16x16x32_bf16(aw, B.b0, a0, 0, 0, 0);
  a1 = __builtin_amdgcn_mfma_f32_16x16x32_bf16(aw, B.b1, a1, 0, 0, 0);
  a2 = __builtin_amdgcn_mfma_f32_16x16x32_bf16(aw, B.b2, a2, 0, 0, 0);
  a3 = __builtin_amdgcn_mfma_f32_16x16x32_bf16(aw, B.b3, a3, 0, 0, 0);
}

__global__ __launch_bounds__(256) void k2_attn(
    const int* __restrict__ adj, const float* __restrict__ srcg,
    const float* __restrict__ dstv, const float* __restrict__ dmax,
    const unsigned short* __restrict__ whT, float* __restrict__ hpart,
    float* __restrict__ spart) {
  int tid = threadIdx.x;
  int lane = tid & 63;
  int wave = tid >> 6;
  int rtile = blockIdx.x * 64 + wave * 16;
  int jy = blockIdx.y;
  int jbase = jy * JCHUNK;
  int m = lane & 15;
  int g = lane >> 4;
  int row = rtile + m;
  float sv = srcg[row];
  float dm = dmax[0];
  float xm = sv + dm;
  float M2 = fmaxf(xm, ALPHA * xm) * LOG2E;
  v4f a0 = {}, a1 = {}, a2 = {}, a3 = {};
  float ssum = 0.f;
  Buf BA, BB;
  loadstep(BA, adj, dstv, whT, row, g, m, jbase);
  for (int t = 0; t < NSTEP; t += 2) {
    loadstep(BB, adj, dstv, whT, row, g, m, jbase + (t + 1) * 32);
    computestep(BA, sv, M2, a0, a1, a2, a3, ssum);
    if (t + 2 < NSTEP)
      loadstep(BA, adj, dstv, whT, row, g, m, jbase + (t + 2) * 32);
    computestep(BB, sv, M2, a0, a1, a2, a3, ssum);
  }
  // row-sum: combine the 4 k-groups (lanes with same (lane&15))
  ssum += __shfl_xor(ssum, 16);
  ssum += __shfl_xor(ssum, 32);
  if (g == 0) spart[jy * NROW + row] = ssum;
  // store partial numerator tile: D row=(g*4+r), col=ct*16+m
  float* hp = hpart + ((long)jy * NROW + rtile) * FOUT;
#pragma unroll
  for (int r = 0; r < 4; ++r) {
    hp[(g * 4 + r) * FOUT + 0 + m] = a0[r];
    hp[(g * 4 + r) * FOUT + 16 + m] = a1[r];
    hp[(g * 4 + r) * FOUT + 32 + m] = a2[r];
    hp[(g * 4 + r) * FOUT + 48 + m] = a3[r];
  }
}

// ---------------- Kernel 3: combine partials, divide, ELU ------------------
__global__ __launch_bounds__(256) void k3_fin(const float* __restrict__ hpart,
                                              const float* __restrict__ spart,
                                              float* __restrict__ out) {
  long gid = (long)blockIdx.x * 256 + threadIdx.x;
  int i = (int)(gid >> 6);
  float num = 0.f, den = 0.f;
#pragma unroll
  for (int p = 0; p < JSPLIT; ++p) {
    num += hpart[(long)p * NROW * FOUT + gid];
    den += spart[p * NROW + i];
  }
  float v = num / den;
  out[gid] = v > 0.f ? v : (__expf(v) - 1.0f);
}

extern "C" void kernel_launch(void* const* d_in, const int* in_sizes, int n_in,
                              void* d_out, int out_size, void* d_ws,
                              size_t ws_size, hipStream_t stream) {
  const float* h = (const float*)d_in[0];
  const float* edge = (const float*)d_in[1];
  const int* adj = (const int*)d_in[2];
  const float* W = (const float*)d_in[3];
  const float* a = (const float*)d_in[4];
  const float* We = (const float*)d_in[5];
  float* out = (float*)d_out;
  char* ws = (char*)d_ws;
  unsigned short* whT = (unsigned short*)ws;           // 1 MB
  float* srcv = (float*)(ws + 1048576);                // 32 KB
  float* dstv = (float*)(ws + 1081344);                // 32 KB
  float* dmax = (float*)(ws + 1114112);                // pad to 256B
  float* spart = (float*)(ws + 1114368);               // 256 KB
  float* hpart = (float*)(ws + 1376512);               // 16 MB
  hipLaunchKernelGGL(k1_proj, dim3(512), dim3(256), 0, stream, h, edge, W, a,
                     We, whT, srcv, dstv);
  hipLaunchKernelGGL(k1b_dstmax, dim3(1), dim3(256), 0, stream, dstv, dmax);
  hipLaunchKernelGGL(k2_attn, dim3(128, JSPLIT), dim3(256), 0, stream, adj,
                     srcv, dstv, dmax, whT, hpart, spart);
  hipLaunchKernelGGL(k3_fin, dim3(2048), dim3(256), 0, stream, hpart, spart,
                     out);
}

// Round 6
// 440.467 us; speedup vs baseline: 1.0488x; 1.0488x over previous
//
#include <hip/hip_runtime.h>

typedef float v4f __attribute__((ext_vector_type(4)));
typedef short v8s __attribute__((ext_vector_type(8)));

#define ALPHA 0.2f
#define LOG2E 1.44269504088896340736f
#define NROW 8192
#define FIN 256
#define FOUT 64
#define JSPLIT 8
#define JCHUNK (NROW / JSPLIT) /* 1024 */
#define NSTEP (JCHUNK / 32)    /* 32 */

static __device__ __forceinline__ unsigned short f2bf(float f) {
  unsigned int u = __builtin_bit_cast(unsigned int, f);
  u += 0x7fff + ((u >> 16) & 1);
  return (unsigned short)(u >> 16);
}
static __device__ __forceinline__ float bf2f(unsigned short s) {
  unsigned int u = ((unsigned int)s) << 16;
  return __builtin_bit_cast(float, u);
}

// ---- Kernel 1: Wh = h@W -> whT tiled [j/32][64][32] bf16; src, dst --------
// 4 rows per WAVE processed simultaneously: each W element read once from LDS
// feeds 4 FMAs (256 ds_read_b32 + 1024 v_fma per wave instead of 1024+1024).
__global__ __launch_bounds__(256) void k1_proj(
    const float* __restrict__ h, const float* __restrict__ edge,
    const float* __restrict__ W, const float* __restrict__ a,
    const float* __restrict__ We, unsigned short* __restrict__ whT,
    float* __restrict__ srcv, float* __restrict__ dstv) {
  __shared__ float Ws[FIN * FOUT];
  int tid = threadIdx.x;
  const float4* Wg = (const float4*)W;
  float4* Wl = (float4*)Ws;
#pragma unroll
  for (int it = 0; it < 16; ++it) Wl[it * 256 + tid] = Wg[it * 256 + tid];
  int lane = tid & 63;
  int wave = tid >> 6;
  float a1c = a[lane], a2c = a[64 + lane], a3c = a[128 + lane];
  float Wer[8];
#pragma unroll
  for (int k = 0; k < 8; ++k) Wer[k] = We[k * 64 + lane];
  __syncthreads();
  int rbase = blockIdx.x * 16 + wave * 4;
  const float* hr0 = h + (long)(rbase + 0) * FIN;
  const float* hr1 = h + (long)(rbase + 1) * FIN;
  const float* hr2 = h + (long)(rbase + 2) * FIN;
  const float* hr3 = h + (long)(rbase + 3) * FIN;
  float acc0 = 0.f, acc1 = 0.f, acc2 = 0.f, acc3 = 0.f;
#pragma unroll 2
  for (int k = 0; k < FIN; k += 4) {
    float4 h0 = *(const float4*)(hr0 + k);
    float4 h1 = *(const float4*)(hr1 + k);
    float4 h2 = *(const float4*)(hr2 + k);
    float4 h3 = *(const float4*)(hr3 + k);
#pragma unroll
    for (int t = 0; t < 4; ++t) {
      float w = Ws[(k + t) * 64 + lane];
      float e0 = (t == 0) ? h0.x : (t == 1) ? h0.y : (t == 2) ? h0.z : h0.w;
      float e1 = (t == 0) ? h1.x : (t == 1) ? h1.y : (t == 2) ? h1.z : h1.w;
      float e2 = (t == 0) ? h2.x : (t == 1) ? h2.y : (t == 2) ? h2.z : h2.w;
      float e3 = (t == 0) ? h3.x : (t == 1) ? h3.y : (t == 2) ? h3.z : h3.w;
      acc0 = __builtin_fmaf(e0, w, acc0);
      acc1 = __builtin_fmaf(e1, w, acc1);
      acc2 = __builtin_fmaf(e2, w, acc2);
      acc3 = __builtin_fmaf(e3, w, acc3);
    }
  }
#pragma unroll
  for (int rr = 0; rr < 4; ++rr) {
    int r = rbase + rr;
    float acc = (rr == 0) ? acc0 : (rr == 1) ? acc1 : (rr == 2) ? acc2 : acc3;
    float4 e0 = *(const float4*)(edge + r * 8);
    float4 e1 = *(const float4*)(edge + r * 8 + 4);
    float aedge = e0.x * Wer[0] + e0.y * Wer[1] + e0.z * Wer[2] +
                  e0.w * Wer[3] + e1.x * Wer[4] + e1.y * Wer[5] +
                  e1.z * Wer[6] + e1.w * Wer[7];
    float ps = acc * a1c + aedge * a3c;
    float pd = acc * a2c;
#pragma unroll
    for (int off = 32; off >= 1; off >>= 1) {
      ps += __shfl_xor(ps, off);
      pd += __shfl_xor(pd, off);
    }
    // tiled layout: whT[(j>>5)*2048 + fout*32 + (j&31)]
    whT[((long)(r >> 5)) * 2048 + lane * 32 + (r & 31)] = f2bf(acc);
    if (lane == 0) {
      srcv[r] = ps;
      dstv[r] = pd;
    }
  }
}

// ---------------- Kernel 1b: global max of dst ----------------------------
__global__ __launch_bounds__(256) void k1b_dstmax(const float* __restrict__ dstv,
                                                  float* __restrict__ dmax) {
  int tid = threadIdx.x;
  float m = -1e30f;
  for (int k = tid; k < NROW; k += 256) m = fmaxf(m, dstv[k]);
#pragma unroll
  for (int off = 32; off >= 1; off >>= 1) m = fmaxf(m, __shfl_xor(m, off));
  __shared__ float red[4];
  if ((tid & 63) == 0) red[tid >> 6] = m;
  __syncthreads();
  if (tid == 0) dmax[0] = fmaxf(fmaxf(red[0], red[1]), fmaxf(red[2], red[3]));
}

// ---------------- Kernel 2: fused masked-softmax-weight x Wh (MFMA) -------
struct Buf {
  int4 aj0, aj1;
  float4 d0, d1;
  v8s b0, b1, b2, b3;
};

static __device__ __forceinline__ void loadstep(
    Buf& B, const int* __restrict__ adj, const float* __restrict__ dstv,
    const unsigned short* __restrict__ whT, int row, int g, int m, int jj) {
  const int* ap = adj + (long)row * NROW + jj + g * 8;
  B.aj0 = *(const int4*)ap;
  B.aj1 = *(const int4*)(ap + 4);
  const float* dp = dstv + jj + g * 8;
  B.d0 = *(const float4*)dp;
  B.d1 = *(const float4*)(dp + 4);
  // tiled whT: tile (jj>>5) is 2048 shorts; fragment c at +c*512; each of
  // the 4 loads below covers a contiguous 1KB across the wave's 64 lanes.
  const unsigned short* wp = whT + ((long)(jj >> 5)) * 2048 + m * 32 + g * 8;
  B.b0 = *(const v8s*)(wp + 0);
  B.b1 = *(const v8s*)(wp + 512);
  B.b2 = *(const v8s*)(wp + 1024);
  B.b3 = *(const v8s*)(wp + 1536);
}

static __device__ __forceinline__ void computestep(const Buf& B, float sv,
                                                   float M2, v4f& a0, v4f& a1,
                                                   v4f& a2, v4f& a3,
                                                   float& ssum) {
  v8s aw;
#define WCALC(adji, dsti, slot)                                 \
  {                                                             \
    float x = sv + (dsti);                                      \
    float lr = fmaxf(x, ALPHA * x);                             \
    float w = exp2f(__builtin_fmaf(lr, LOG2E, -M2));            \
    unsigned short wb = ((adji) > 0) ? f2bf(w) : (unsigned short)0; \
    ssum += bf2f(wb);                                           \
    aw[slot] = (short)wb;                                       \
  }
  WCALC(B.aj0.x, B.d0.x, 0)
  WCALC(B.aj0.y, B.d0.y, 1)
  WCALC(B.aj0.z, B.d0.z, 2)
  WCALC(B.aj0.w, B.d0.w, 3)
  WCALC(B.aj1.x, B.d1.x, 4)
  WCALC(B.aj1.y, B.d1.y, 5)
  WCALC(B.aj1.z, B.d1.z, 6)
  WCALC(B.aj1.w, B.d1.w, 7)
#undef WCALC
  a0 = __builtin_amdgcn_mfma_f32_16x16x32_bf16(aw, B.b0, a0, 0, 0, 0);
  a1 = __builtin_amdgcn_mfma_f32_16x16x32_bf16(aw, B.b1, a1, 0, 0, 0);
  a2 = __builtin_amdgcn_mfma_f32_16x16x32_bf16(aw, B.b2, a2, 0, 0, 0);
  a3 = __builtin_amdgcn_mfma_f32_16x16x32_bf16(aw, B.b3, a3, 0, 0, 0);
}

__global__ __launch_bounds__(256) void k2_attn(
    const int* __restrict__ adj, const float* __restrict__ srcg,
    const float* __restrict__ dstv, const float* __restrict__ dmax,
    const unsigned short* __restrict__ whT, float* __restrict__ hpart,
    float* __restrict__ spart) {
  int tid = threadIdx.x;
  int lane = tid & 63;
  int wave = tid >> 6;
  int rtile = blockIdx.x * 64 + wave * 16;
  int jy = blockIdx.y;
  int jbase = jy * JCHUNK;
  int m = lane & 15;
  int g = lane >> 4;
  int row = rtile + m;
  float sv = srcg[row];
  float dm = dmax[0];
  float xm = sv + dm;
  float M2 = fmaxf(xm, ALPHA * xm) * LOG2E;
  v4f a0 = {}, a1 = {}, a2 = {}, a3 = {};
  float ssum = 0.f;
  Buf BA, BB;
  loadstep(BA, adj, dstv, whT, row, g, m, jbase);
  for (int t = 0; t < NSTEP; t += 2) {
    loadstep(BB, adj, dstv, whT, row, g, m, jbase + (t + 1) * 32);
    computestep(BA, sv, M2, a0, a1, a2, a3, ssum);
    if (t + 2 < NSTEP)
      loadstep(BA, adj, dstv, whT, row, g, m, jbase + (t + 2) * 32);
    computestep(BB, sv, M2, a0, a1, a2, a3, ssum);
  }
  // row-sum: combine the 4 k-groups (lanes with same (lane&15))
  ssum += __shfl_xor(ssum, 16);
  ssum += __shfl_xor(ssum, 32);
  if (g == 0) spart[jy * NROW + row] = ssum;
  // store partial numerator tile: D row=(g*4+r), col=ct*16+m
  float* hp = hpart + ((long)jy * NROW + rtile) * FOUT;
#pragma unroll
  for (int r = 0; r < 4; ++r) {
    hp[(g * 4 + r) * FOUT + 0 + m] = a0[r];
    hp[(g * 4 + r) * FOUT + 16 + m] = a1[r];
    hp[(g * 4 + r) * FOUT + 32 + m] = a2[r];
    hp[(g * 4 + r) * FOUT + 48 + m] = a3[r];
  }
}

// ---------------- Kernel 3: combine partials, divide, ELU ------------------
__global__ __launch_bounds__(256) void k3_fin(const float* __restrict__ hpart,
                                              const float* __restrict__ spart,
                                              float* __restrict__ out) {
  long gid = (long)blockIdx.x * 256 + threadIdx.x;
  int i = (int)(gid >> 6);
  float num = 0.f, den = 0.f;
#pragma unroll
  for (int p = 0; p < JSPLIT; ++p) {
    num += hpart[(long)p * NROW * FOUT + gid];
    den += spart[p * NROW + i];
  }
  float v = num / den;
  out[gid] = v > 0.f ? v : (__expf(v) - 1.0f);
}

extern "C" void kernel_launch(void* const* d_in, const int* in_sizes, int n_in,
                              void* d_out, int out_size, void* d_ws,
                              size_t ws_size, hipStream_t stream) {
  const float* h = (const float*)d_in[0];
  const float* edge = (const float*)d_in[1];
  const int* adj = (const int*)d_in[2];
  const float* W = (const float*)d_in[3];
  const float* a = (const float*)d_in[4];
  const float* We = (const float*)d_in[5];
  float* out = (float*)d_out;
  char* ws = (char*)d_ws;
  unsigned short* whT = (unsigned short*)ws;           // 1 MB (tiled)
  float* srcv = (float*)(ws + 1048576);                // 32 KB
  float* dstv = (float*)(ws + 1081344);                // 32 KB
  float* dmax = (float*)(ws + 1114112);                // pad to 256B
  float* spart = (float*)(ws + 1114368);               // 256 KB
  float* hpart = (float*)(ws + 1376512);               // 16 MB
  hipLaunchKernelGGL(k1_proj, dim3(512), dim3(256), 0, stream, h, edge, W, a,
                     We, whT, srcv, dstv);
  hipLaunchKernelGGL(k1b_dstmax, dim3(1), dim3(256), 0, stream, dstv, dmax);
  hipLaunchKernelGGL(k2_attn, dim3(128, JSPLIT), dim3(256), 0, stream, adj,
                     srcv, dstv, dmax, whT, hpart, spart);
  hipLaunchKernelGGL(k3_fin, dim3(2048), dim3(256), 0, stream, hpart, spart,
                     out);
}